// Round 1
// baseline (29.556 us; speedup 1.0000x reference)
//
#include <hip/hip_runtime.h>
#include <math.h>

// Problem constants (B=4, T=S=512, M=N=512, H=128)
#define HDIM 128
#define KDIM 512
#define ROWS 8
#define TOTAL_ROWS 2048   // B*T == B*S
#define TDIM 512
#define SDIM 512

// score[b,t,s] = ( sum_h v[h]*tanh(q[b,t,:]·W2[h,:]) + sum_h v[H+h]*tanh(k[b,s,:]·W1[h,:]) ) / sqrt(512)
// => separable: a[b,t] + c[b,s], scaled.

__global__ __launch_bounds__(256) void proj_kernel(
    const float* __restrict__ query, const float* __restrict__ keys,
    const float* __restrict__ W1, const float* __restrict__ W2,
    const float* __restrict__ v, float* __restrict__ ws)
{
    // blocks [0, 256): query rows with W2, v[0:128]   -> ws[0:2048]      (a)
    // blocks [256,512): keys  rows with W1, v[128:256]-> ws[2048:4096]   (c)
    const int blk = blockIdx.x;
    const int blocks_per_tensor = TOTAL_ROWS / ROWS;  // 256
    const bool is_keys = (blk >= blocks_per_tensor);
    const float* __restrict__ X  = is_keys ? keys : query;
    const float* __restrict__ W  = is_keys ? W1 : W2;
    const float* __restrict__ vv = v + (is_keys ? HDIM : 0);
    float* __restrict__ out = ws + (is_keys ? TOTAL_ROWS : 0);
    const int row0 = (is_keys ? (blk - blocks_per_tensor) : blk) * ROWS;

    __shared__ float sm[ROWS][KDIM];       // 16 KB
    __shared__ float sm_part[4][ROWS];     // wave partials

    const int tid = threadIdx.x;

    // Stage ROWS*KDIM = 4096 floats: 256 threads x 4 float4
    {
        const float4* __restrict__ src = (const float4*)(X + (size_t)row0 * KDIM);
        float4* dst = (float4*)(&sm[0][0]);
        #pragma unroll
        for (int i = 0; i < 4; ++i)
            dst[tid + i * 256] = src[tid + i * 256];
    }
    __syncthreads();

    const int h    = tid >> 1;    // 0..127
    const int half = tid & 1;     // 0: k[0,256), 1: k[256,512)
    const float4* __restrict__ Wp = (const float4*)(W + (size_t)h * KDIM + half * (KDIM / 2));

    float acc[ROWS];
    #pragma unroll
    for (int r = 0; r < ROWS; ++r) acc[r] = 0.0f;

    #pragma unroll 4
    for (int j = 0; j < (KDIM / 2) / 4; ++j) {   // 64 iterations
        const float4 w = Wp[j];
        #pragma unroll
        for (int r = 0; r < ROWS; ++r) {
            const float4 x = ((const float4*)(&sm[r][half * (KDIM / 2)]))[j];
            acc[r] = fmaf(w.x, x.x, acc[r]);
            acc[r] = fmaf(w.y, x.y, acc[r]);
            acc[r] = fmaf(w.z, x.z, acc[r]);
            acc[r] = fmaf(w.w, x.w, acc[r]);
        }
    }

    // Combine the two k-halves (lanes tid and tid^1 are in the same wave64)
    const float vh = vv[h];
    float val[ROWS];
    #pragma unroll
    for (int r = 0; r < ROWS; ++r) {
        const float tot = acc[r] + __shfl_xor(acc[r], 1, 64);
        val[r] = (half == 0) ? vh * tanhf(tot) : 0.0f;
    }

    // Wave-level reduce across 64 lanes (odd lanes contribute 0).
    // Parity-preserving masks 2,4,8,16,32 bring the even-lane sum to lane 0.
    #pragma unroll
    for (int r = 0; r < ROWS; ++r) {
        float s = val[r];
        s += __shfl_xor(s, 2, 64);
        s += __shfl_xor(s, 4, 64);
        s += __shfl_xor(s, 8, 64);
        s += __shfl_xor(s, 16, 64);
        s += __shfl_xor(s, 32, 64);
        if ((tid & 63) == 0) sm_part[tid >> 6][r] = s;
    }
    __syncthreads();

    if (tid < ROWS) {
        float s = sm_part[0][tid] + sm_part[1][tid] + sm_part[2][tid] + sm_part[3][tid];
        out[row0 + tid] = s;
    }
}

__global__ __launch_bounds__(128) void outer_kernel(
    const float* __restrict__ ws, float* __restrict__ out)
{
    // block = b*T + t; threads cover S=512 via float4
    const int bt = blockIdx.x;                  // 0..2047
    const float a = ws[bt];
    const int b = bt >> 9;                      // / T
    const float4* __restrict__ c4 = (const float4*)(ws + TOTAL_ROWS + (size_t)b * SDIM);
    const float inv_scale = 0.04419417382415922f;  // 1/sqrt(512)

    const float4 cv = c4[threadIdx.x];
    float4 o;
    o.x = (a + cv.x) * inv_scale;
    o.y = (a + cv.y) * inv_scale;
    o.z = (a + cv.z) * inv_scale;
    o.w = (a + cv.w) * inv_scale;
    ((float4*)out)[(size_t)bt * (SDIM / 4) + threadIdx.x] = o;
}

extern "C" void kernel_launch(void* const* d_in, const int* in_sizes, int n_in,
                              void* d_out, int out_size, void* d_ws, size_t ws_size,
                              hipStream_t stream) {
    const float* query = (const float*)d_in[0];  // (4,512,512)
    const float* keys  = (const float*)d_in[1];  // (4,512,512)
    const float* W1    = (const float*)d_in[2];  // (128,512)
    const float* W2    = (const float*)d_in[3];  // (128,512)
    const float* v     = (const float*)d_in[4];  // (1,256)
    float* out = (float*)d_out;                  // (4,512,512)
    float* ws  = (float*)d_ws;                   // need 4096 floats = 16 KB

    proj_kernel<<<2 * (TOTAL_ROWS / ROWS), 256, 0, stream>>>(query, keys, W1, W2, v, ws);
    outer_kernel<<<TOTAL_ROWS, 128, 0, stream>>>(ws, out);
}

// Round 2
// 21.211 us; speedup vs baseline: 1.3934x; 1.3934x over previous
//
#include <hip/hip_runtime.h>
#include <math.h>

// Problem constants (B=4, T=S=512, M=N=512, H=128)
#define HDIM 128
#define KDIM 512
#define ROWS 16          // rows per proj block
#define TOTAL_ROWS 2048  // B*T == B*S
#define SDIM 512

// score[b,t,s] = ( sum_h v[h]*tanh(q[b,t,:]·W2[h,:]) + sum_h v[H+h]*tanh(k[b,s,:]·W1[h,:]) ) / sqrt(512)
// separable: (a[b,t] + c[b,s]) * inv_scale

__device__ __forceinline__ float fast_tanh(float x) {
    // tanh(x) = 1 - 2/(e^{2x}+1); graceful at +/-inf, ~1e-7 abs error
    float e = __expf(2.0f * x);
    return 1.0f - 2.0f / (e + 1.0f);
}

__global__ __launch_bounds__(512, 2) void proj_kernel(
    const float* __restrict__ query, const float* __restrict__ keys,
    const float* __restrict__ W1, const float* __restrict__ W2,
    const float* __restrict__ v, float* __restrict__ ws)
{
    // blocks [0,128): query rows w/ W2, v[0:128]   -> ws[0:2048]    (a)
    // blocks [128,256): keys rows w/ W1, v[128:256]-> ws[2048:4096] (c)
    const int blk = blockIdx.x;
    const int bpt = TOTAL_ROWS / ROWS;  // 128
    const bool is_keys = (blk >= bpt);
    const float* __restrict__ X  = is_keys ? keys : query;
    const float* __restrict__ W  = is_keys ? W1 : W2;
    const float* __restrict__ vv = v + (is_keys ? HDIM : 0);
    float* __restrict__ out = ws + (is_keys ? TOTAL_ROWS : 0);
    const int row0 = (is_keys ? (blk - bpt) : blk) * ROWS;

    __shared__ float sm_x[ROWS][KDIM];   // 32 KB
    __shared__ float sm_p[8][8];         // [wave][r] partials

    const int tid  = threadIdx.x;
    const int ks   = tid & 7;          // K-split slot (interleaved, lane bits 0-2)
    const int hg   = (tid >> 3) & 31;  // h-group: 4 h's each (lane bits 3-5 + wave bits)
    const int rowg = tid >> 8;         // row half: 8 rows each

    // Stage X tile: ROWS*KDIM = 8192 floats = 2048 float4; 512 threads x 4
    {
        const float4* __restrict__ src = (const float4*)(X + (size_t)row0 * KDIM);
        float4* dst = (float4*)(&sm_x[0][0]);
        #pragma unroll
        for (int i = 0; i < 4; ++i)
            dst[tid + i * 512] = src[tid + i * 512];
    }
    __syncthreads();

    const float* __restrict__ wbase = W + (size_t)(hg * 4) * KDIM;
    const float* __restrict__ xbase = &sm_x[rowg * 8][0];

    float acc[8][4];
    #pragma unroll
    for (int r = 0; r < 8; ++r)
        #pragma unroll
        for (int hh = 0; hh < 4; ++hh) acc[r][hh] = 0.0f;

    // Thread covers K columns {jj*32 + ks*4 .. +3}, jj = 0..15 (64 of 512 K)
    #pragma unroll 2
    for (int jj = 0; jj < 16; ++jj) {
        const int col = jj * 32 + ks * 4;
        const float4 w0 = *(const float4*)(wbase + 0 * KDIM + col);
        const float4 w1 = *(const float4*)(wbase + 1 * KDIM + col);
        const float4 w2 = *(const float4*)(wbase + 2 * KDIM + col);
        const float4 w3 = *(const float4*)(wbase + 3 * KDIM + col);
        #pragma unroll
        for (int r = 0; r < 8; ++r) {
            const float4 x = *(const float4*)(xbase + r * KDIM + col);
            acc[r][0] = fmaf(x.x, w0.x, acc[r][0]);
            acc[r][0] = fmaf(x.y, w0.y, acc[r][0]);
            acc[r][0] = fmaf(x.z, w0.z, acc[r][0]);
            acc[r][0] = fmaf(x.w, w0.w, acc[r][0]);
            acc[r][1] = fmaf(x.x, w1.x, acc[r][1]);
            acc[r][1] = fmaf(x.y, w1.y, acc[r][1]);
            acc[r][1] = fmaf(x.z, w1.z, acc[r][1]);
            acc[r][1] = fmaf(x.w, w1.w, acc[r][1]);
            acc[r][2] = fmaf(x.x, w2.x, acc[r][2]);
            acc[r][2] = fmaf(x.y, w2.y, acc[r][2]);
            acc[r][2] = fmaf(x.z, w2.z, acc[r][2]);
            acc[r][2] = fmaf(x.w, w2.w, acc[r][2]);
            acc[r][3] = fmaf(x.x, w3.x, acc[r][3]);
            acc[r][3] = fmaf(x.y, w3.y, acc[r][3]);
            acc[r][3] = fmaf(x.z, w3.z, acc[r][3]);
            acc[r][3] = fmaf(x.w, w3.w, acc[r][3]);
        }
    }

    // K-split reduce across ks (lane bits 0-2) -> every lane holds full dots
    #pragma unroll
    for (int r = 0; r < 8; ++r)
        #pragma unroll
        for (int hh = 0; hh < 4; ++hh) {
            float s = acc[r][hh];
            s += __shfl_xor(s, 1, 64);
            s += __shfl_xor(s, 2, 64);
            s += __shfl_xor(s, 4, 64);
            acc[r][hh] = s;
        }

    const float4 vh = *(const float4*)(vv + hg * 4);

    const int wave = tid >> 6;
    const int lane = tid & 63;
    #pragma unroll
    for (int r = 0; r < 8; ++r) {
        float rs = vh.x * fast_tanh(acc[r][0])
                 + vh.y * fast_tanh(acc[r][1])
                 + vh.z * fast_tanh(acc[r][2])
                 + vh.w * fast_tanh(acc[r][3]);
        // reduce over hg low bits (lane bits 3-5): 8 h-groups in this wave
        rs += __shfl_xor(rs, 8, 64);
        rs += __shfl_xor(rs, 16, 64);
        rs += __shfl_xor(rs, 32, 64);
        if (lane == 0) sm_p[wave][r] = rs;
    }
    __syncthreads();

    // rows 0..7 from waves 0..3, rows 8..15 from waves 4..7
    if (tid < ROWS) {
        const int rg = tid >> 3, r = tid & 7;
        const float s = sm_p[rg * 4 + 0][r] + sm_p[rg * 4 + 1][r]
                      + sm_p[rg * 4 + 2][r] + sm_p[rg * 4 + 3][r];
        out[row0 + tid] = s;
    }
}

__global__ __launch_bounds__(128) void outer_kernel(
    const float* __restrict__ ws, float* __restrict__ out)
{
    // block = b*T + t; threads cover S=512 via float4
    const int bt = blockIdx.x;                  // 0..2047
    const float a = ws[bt];
    const int b = bt >> 9;                      // / T
    const float4* __restrict__ c4 = (const float4*)(ws + TOTAL_ROWS + (size_t)b * SDIM);
    const float inv_scale = 0.04419417382415922f;  // 1/sqrt(512)

    const float4 cv = c4[threadIdx.x];
    float4 o;
    o.x = (a + cv.x) * inv_scale;
    o.y = (a + cv.y) * inv_scale;
    o.z = (a + cv.z) * inv_scale;
    o.w = (a + cv.w) * inv_scale;
    ((float4*)out)[(size_t)bt * (SDIM / 4) + threadIdx.x] = o;
}

extern "C" void kernel_launch(void* const* d_in, const int* in_sizes, int n_in,
                              void* d_out, int out_size, void* d_ws, size_t ws_size,
                              hipStream_t stream) {
    const float* query = (const float*)d_in[0];  // (4,512,512)
    const float* keys  = (const float*)d_in[1];  // (4,512,512)
    const float* W1    = (const float*)d_in[2];  // (128,512)
    const float* W2    = (const float*)d_in[3];  // (128,512)
    const float* v     = (const float*)d_in[4];  // (1,256)
    float* out = (float*)d_out;                  // (4,512,512)
    float* ws  = (float*)d_ws;                   // 4096 floats = 16 KB

    proj_kernel<<<2 * (TOTAL_ROWS / ROWS), 512, 0, stream>>>(query, keys, W1, W2, v, ws);
    outer_kernel<<<TOTAL_ROWS, 128, 0, stream>>>(ws, out);
}